// Round 12
// baseline (281.722 us; speedup 1.0000x reference)
//
#include <hip/hip_runtime.h>
#include <hip/hip_bf16.h>

// BiGAT: 2-layer GAT forward.
// N=50000, IN_CH=128, HID=32, HEADS=8, NCLS=16, E=800000 (+N self loops).
// R12: agg1 fused gemm2 tail rebuilt LDS-free (coalesced W2t32 global loads +
// 52-shuffle reduction) -> no bank conflicts, LDS=0; H2+ES2 fused into one
// 128B row (H2p[n][32], es at slot 16) halving agg2's scattered streams.

#define IN_CH 128
#define HIDC  256   // HEADS*HID
#define NCLS  16
#define NEG_SLOPE 0.2f

typedef short bf16x8 __attribute__((ext_vector_type(8)));
typedef float f32x4 __attribute__((ext_vector_type(4)));

__device__ __forceinline__ unsigned int f2bf(float f) {
    unsigned int u = __float_as_uint(f);
    return (u + 0x7fffu + ((u >> 16) & 1u)) >> 16;
}
__device__ __forceinline__ float bf_lo(unsigned int w) { return __uint_as_float(w << 16); }
__device__ __forceinline__ float bf_hi(unsigned int w) { return __uint_as_float(w & 0xffff0000u); }

// ---------------- CSR: count(+rank) + fills + W1/W2 transposes ----------------

__global__ void count_fill_kernel(const int* __restrict__ ei, int* __restrict__ counts,
                                  int* __restrict__ erank, int E, int Etot,
                                  int* __restrict__ colB, int fill_n, int dummyB,
                                  unsigned short* __restrict__ Hb, float* __restrict__ ES1,
                                  float* __restrict__ H2p,
                                  const float* __restrict__ W1,
                                  unsigned short* __restrict__ W1t,
                                  const float* __restrict__ W2,
                                  float* __restrict__ W2t32, int N) {
    int i = blockIdx.x * blockDim.x + threadIdx.x;
    if (i < Etot) {
        int dst = (i < E) ? ei[E + i] : (i - E);
        erank[i] = atomicAdd(&counts[dst], 1);
    }
    if (i < fill_n) colB[i] = dummyB;
    if (i < IN_CH * HIDC) {   // W1t[c][k] = bf16(W1[k][c])
        int c = i >> 7, k = i & 127;
        W1t[i] = (unsigned short)f2bf(W1[k * HIDC + c]);
    }
    if (i < HIDC * NCLS) {    // W2t32[c][k] = W2[k][c]
        int c = i >> 8, k = i & 255;
        W2t32[i] = W2[k * NCLS + c];
    }
    if (i < HIDC) Hb[(size_t)N * HIDC + i] = 0;
    if (i < 32) H2p[(size_t)N * 32 + i] = (i == 16) ? -3.0e38f : 0.f;
    if (i < 8) ES1[(size_t)N * 8 + i] = -3.0e38f;
}

// ---------------- 3-phase exclusive scan over padded counts ((c+3)&~3) ----------------

__global__ __launch_bounds__(256) void scanA_kernel(const int* __restrict__ counts,
                                                    int* __restrict__ row_start,
                                                    int* __restrict__ bsums, int n) {
    __shared__ int wsum[4];
    int tid = threadIdx.x, lane = tid & 63, wid = tid >> 6;
    int i = blockIdx.x * 256 + tid;
    int v = (i < n) ? ((counts[i] + 3) & ~3) : 0;
    int x = v;
    #pragma unroll
    for (int off = 1; off < 64; off <<= 1) {
        int t = __shfl_up(x, off);
        if (lane >= off) x += t;
    }
    if (lane == 63) wsum[wid] = x;
    __syncthreads();
    if (tid < 4) {
        int w = wsum[tid];
        #pragma unroll
        for (int off = 1; off < 4; off <<= 1) {
            int t = __shfl_up(w, off);
            if (tid >= off) w += t;
        }
        wsum[tid] = w;
    }
    __syncthreads();
    int wex = wid ? wsum[wid - 1] : 0;
    if (i < n) row_start[i] = wex + (x - v);
    if (tid == 255) bsums[blockIdx.x] = wsum[3];
}

__global__ __launch_bounds__(256) void scanB_kernel(const int* __restrict__ bsums,
                                                    int* __restrict__ bofs,
                                                    int* __restrict__ row_start,
                                                    int nb, int n) {
    __shared__ int wsum[4];
    int tid = threadIdx.x, lane = tid & 63, wid = tid >> 6;
    int v = (tid < nb) ? bsums[tid] : 0;
    int x = v;
    #pragma unroll
    for (int off = 1; off < 64; off <<= 1) {
        int t = __shfl_up(x, off);
        if (lane >= off) x += t;
    }
    if (lane == 63) wsum[wid] = x;
    __syncthreads();
    if (tid < 4) {
        int w = wsum[tid];
        #pragma unroll
        for (int off = 1; off < 4; off <<= 1) {
            int t = __shfl_up(w, off);
            if (tid >= off) w += t;
        }
        wsum[tid] = w;
    }
    __syncthreads();
    int wex = wid ? wsum[wid - 1] : 0;
    if (tid < nb) bofs[tid] = wex + (x - v);
    if (tid == nb - 1) row_start[n] = wex + x;
}

__global__ __launch_bounds__(256) void scanC_kernel(int* __restrict__ row_start,
                                                    const int* __restrict__ bofs, int n) {
    int i = blockIdx.x * 256 + threadIdx.x;
    if (i < n) row_start[i] += bofs[blockIdx.x];
}

// atomic-free scatter: pos = row_start[dst] + precomputed rank
__global__ void scatter_kernel(const int* __restrict__ ei, const int* __restrict__ row_start,
                               const int* __restrict__ erank, int* __restrict__ colB,
                               int E, int Etot) {
    int e = blockIdx.x * blockDim.x + threadIdx.x;
    if (e >= Etot) return;
    int src, dst;
    if (e < E) { src = ei[e]; dst = ei[E + e]; }
    else       { src = e - E; dst = e - E; }
    colB[row_start[dst] + erank[e]] = src * (HIDC * 2);
}

// ---------------- GEMM1 (MFMA bf16) + fused att1 ----------------

#define LDK 72   // 64 k + 8 pad (bf16 elems)

__global__ __launch_bounds__(256) void gemm1_mfma(const float* __restrict__ A,
                                                  const unsigned short* __restrict__ W1t,
                                                  const float* __restrict__ a_src,
                                                  const float* __restrict__ a_dst,
                                                  unsigned short* __restrict__ Hb,
                                                  float* __restrict__ ES,
                                                  float* __restrict__ ED, int M) {
    __shared__ unsigned short As[128 * LDK];
    __shared__ unsigned short Bs[128 * LDK];
    int tid = threadIdx.x;
    int row0 = blockIdx.x * 128, col0 = blockIdx.y * 128;
    int lane = tid & 63, wid = tid >> 6;
    int wr = wid >> 1, wc = wid & 1;
    int la = lane & 15, lg = lane >> 4;
    f32x4 acc[4][4] = {};

    int r = tid >> 1, hf = tid & 1;
    int gr = row0 + r;
    bool okA = gr < M;
    const float4* asrc = reinterpret_cast<const float4*>(A + (size_t)(okA ? gr : 0) * IN_CH) + hf * 8;
    const uint4*  bsrc = reinterpret_cast<const uint4*>(W1t + (size_t)(col0 + r) * IN_CH) + hf * 4;
    unsigned short* adst = &As[r * LDK + hf * 32];
    unsigned short* bdst = &Bs[r * LDK + hf * 32];

    #pragma unroll
    for (int kt = 0; kt < 2; ++kt) {
        #pragma unroll
        for (int it = 0; it < 8; ++it) {
            float4 v = okA ? asrc[it] : make_float4(0.f, 0.f, 0.f, 0.f);
            uint2 w;
            w.x = f2bf(v.x) | (f2bf(v.y) << 16);
            w.y = f2bf(v.z) | (f2bf(v.w) << 16);
            *reinterpret_cast<uint2*>(adst + it * 4) = w;
        }
        #pragma unroll
        for (int it = 0; it < 4; ++it) {
            uint4 v = bsrc[it];
            *reinterpret_cast<uint4*>(bdst + it * 8) = v;
        }
        asrc += 16;
        bsrc += 8;
        __syncthreads();
        #pragma unroll
        for (int k0 = 0; k0 < 64; k0 += 32) {
            bf16x8 af[4], bfr[4];
            #pragma unroll
            for (int m = 0; m < 4; ++m)
                af[m] = *reinterpret_cast<const bf16x8*>(&As[(wr * 64 + m * 16 + la) * LDK + k0 + lg * 8]);
            #pragma unroll
            for (int n2 = 0; n2 < 4; ++n2)
                bfr[n2] = *reinterpret_cast<const bf16x8*>(&Bs[(wc * 64 + n2 * 16 + la) * LDK + k0 + lg * 8]);
            #pragma unroll
            for (int m = 0; m < 4; ++m) {
                #pragma unroll
                for (int n2 = 0; n2 < 4; ++n2)
                    acc[m][n2] = __builtin_amdgcn_mfma_f32_16x16x32_bf16(af[m], bfr[n2], acc[m][n2], 0, 0, 0);
            }
        }
        __syncthreads();
    }

    #pragma unroll
    for (int m = 0; m < 4; ++m) {
        #pragma unroll
        for (int j = 0; j < 4; ++j) {
            int grow = row0 + wr * 64 + m * 16 + lg * 4 + j;
            if (grow < M) {
                int gcol = col0 + wc * 64 + la;
                #pragma unroll
                for (int n2 = 0; n2 < 4; ++n2)
                    Hb[(size_t)grow * HIDC + gcol + n2 * 16] = (unsigned short)f2bf(acc[m][n2][j]);
            }
        }
    }

    // fused att1: wave covers heads h0,h0+1
    int h0 = (col0 + wc * 64) >> 5;
    float as00 = a_src[h0 * 32 + la],        as01 = a_src[h0 * 32 + 16 + la];
    float ad00 = a_dst[h0 * 32 + la],        ad01 = a_dst[h0 * 32 + 16 + la];
    float as10 = a_src[(h0 + 1) * 32 + la],  as11 = a_src[(h0 + 1) * 32 + 16 + la];
    float ad10 = a_dst[(h0 + 1) * 32 + la],  ad11 = a_dst[(h0 + 1) * 32 + 16 + la];
    #pragma unroll
    for (int m = 0; m < 4; ++m) {
        #pragma unroll
        for (int j = 0; j < 4; ++j) {
            float v0 = acc[m][0][j], v1 = acc[m][1][j];
            float v2 = acc[m][2][j], v3 = acc[m][3][j];
            float es0 = v0 * as00 + v1 * as01;
            float ed0 = v0 * ad00 + v1 * ad01;
            float es1 = v2 * as10 + v3 * as11;
            float ed1 = v2 * ad10 + v3 * ad11;
            #pragma unroll
            for (int off = 1; off < 16; off <<= 1) {
                es0 += __shfl_xor(es0, off);
                ed0 += __shfl_xor(ed0, off);
                es1 += __shfl_xor(es1, off);
                ed1 += __shfl_xor(ed1, off);
            }
            int grow = row0 + wr * 64 + m * 16 + lg * 4 + j;
            if (la == 0 && grow < M) {
                ES[grow * 8 + h0] = es0;
                ED[grow * 8 + h0] = ed0;
                ES[grow * 8 + h0 + 1] = es1;
                ED[grow * 8 + h0 + 1] = ed1;
            }
        }
    }
}

// ---------------- agg1 + fused gemm2/att2 (LDS-free tail) ----------------

#define EDGE4(cbv)                                                              \
    {                                                                           \
        float e0 = *(const float*)(ESb + (((cbv).x >> 4) | hoff));              \
        float e1 = *(const float*)(ESb + (((cbv).y >> 4) | hoff));              \
        float e2 = *(const float*)(ESb + (((cbv).z >> 4) | hoff));              \
        float e3 = *(const float*)(ESb + (((cbv).w >> 4) | hoff));              \
        uint2 v0 = *(const uint2*)(Hbb + ((cbv).x + lane8));                    \
        uint2 v1 = *(const uint2*)(Hbb + ((cbv).y + lane8));                    \
        uint2 v2 = *(const uint2*)(Hbb + ((cbv).z + lane8));                    \
        uint2 v3 = *(const uint2*)(Hbb + ((cbv).w + lane8));                    \
        e0 += ed; e1 += ed; e2 += ed; e3 += ed;                                 \
        e0 = fmaxf(e0, NEG_SLOPE * e0);                                         \
        e1 = fmaxf(e1, NEG_SLOPE * e1);                                         \
        e2 = fmaxf(e2, NEG_SLOPE * e2);                                         \
        e3 = fmaxf(e3, NEG_SLOPE * e3);                                         \
        float p0 = __expf(e0), p1 = __expf(e1), p2 = __expf(e2), p3 = __expf(e3);\
        s += (p0 + p1) + (p2 + p3);                                             \
        acc.x = fmaf(p0, bf_lo(v0.x), acc.x);                                   \
        acc.y = fmaf(p0, bf_hi(v0.x), acc.y);                                   \
        acc.z = fmaf(p0, bf_lo(v0.y), acc.z);                                   \
        acc.w = fmaf(p0, bf_hi(v0.y), acc.w);                                   \
        acc.x = fmaf(p1, bf_lo(v1.x), acc.x);                                   \
        acc.y = fmaf(p1, bf_hi(v1.x), acc.y);                                   \
        acc.z = fmaf(p1, bf_lo(v1.y), acc.z);                                   \
        acc.w = fmaf(p1, bf_hi(v1.y), acc.w);                                   \
        acc.x = fmaf(p2, bf_lo(v2.x), acc.x);                                   \
        acc.y = fmaf(p2, bf_hi(v2.x), acc.y);                                   \
        acc.z = fmaf(p2, bf_lo(v2.y), acc.z);                                   \
        acc.w = fmaf(p2, bf_hi(v2.y), acc.w);                                   \
        acc.x = fmaf(p3, bf_lo(v3.x), acc.x);                                   \
        acc.y = fmaf(p3, bf_hi(v3.x), acc.y);                                   \
        acc.z = fmaf(p3, bf_lo(v3.y), acc.z);                                   \
        acc.w = fmaf(p3, bf_hi(v3.y), acc.w);                                   \
    }

__global__ __launch_bounds__(256) void agg1_kernel(const unsigned short* __restrict__ Hb,
                                                   const float* __restrict__ ES,
                                                   const float* __restrict__ ED,
                                                   const int* __restrict__ row_start,
                                                   const int* __restrict__ colB,
                                                   const float* __restrict__ b1,
                                                   const float* __restrict__ W2t32,
                                                   const float* __restrict__ as2,
                                                   const float* __restrict__ ad2,
                                                   float* __restrict__ H2p,
                                                   float* __restrict__ ED2, int N) {
    int tid = threadIdx.x;
    int n = blockIdx.x * 4 + (tid >> 6);
    if (n >= N) return;
    int lane = tid & 63;
    int h = lane >> 3;
    unsigned int hoff = h << 2;
    unsigned int lane8 = lane << 3;
    int s0 = row_start[n], s1 = row_start[n + 1];
    float ed = ED[n * 8 + h];
    const char* ESb = (const char*)ES;
    const char* Hbb = (const char*)Hb;

    float s = 0.f;
    float4 acc = make_float4(0.f, 0.f, 0.f, 0.f);

    int i = s0;
    for (; i + 7 < s1; i += 8) {
        uint4 cbA = *reinterpret_cast<const uint4*>(&colB[i]);
        uint4 cbB = *reinterpret_cast<const uint4*>(&colB[i + 4]);
        EDGE4(cbA);
        EDGE4(cbB);
    }
    if (i < s1) {
        uint4 cb = *reinterpret_cast<const uint4*>(&colB[i]);
        EDGE4(cb);
    }

    float inv = 1.0f / s;
    const float4 bv = *reinterpret_cast<const float4*>(&b1[lane * 4]);
    float4 o;
    o.x = acc.x * inv + bv.x;
    o.y = acc.y * inv + bv.y;
    o.z = acc.z * inv + bv.z;
    o.w = acc.w * inv + bv.w;
    o.x = o.x > 0.f ? o.x : expm1f(o.x);
    o.y = o.y > 0.f ? o.y : expm1f(o.y);
    o.z = o.z > 0.f ? o.z : expm1f(o.z);
    o.w = o.w > 0.f ? o.w : expm1f(o.w);

    // ---- fused gemm2/att2: lane owns k=4*lane..+3 (o). Coalesced W2t32 loads,
    // shuffle-tree reduction; no LDS. ----
    {
        const float4* w4 = reinterpret_cast<const float4*>(W2t32) + lane;
        float p[16];
        #pragma unroll
        for (int c = 0; c < 16; ++c) {
            float4 w = w4[c * 64];   // W2t32[c][4*lane .. +3], coalesced per c
            p[c] = o.x * w.x + o.y * w.y + o.z * w.z + o.w * w.w;
        }
        #pragma unroll
        for (int c = 0; c < 16; ++c) {
            p[c] += __shfl_xor(p[c], 32);
            p[c] += __shfl_xor(p[c], 16);
        }
        // quarter q owns cols 4q..4q+3 (constant-index selection)
        int q = lane >> 4;
        float a0 = q < 2 ? (q == 0 ? p[0] : p[4])  : (q == 2 ? p[8]  : p[12]);
        float a1 = q < 2 ? (q == 0 ? p[1] : p[5])  : (q == 2 ? p[9]  : p[13]);
        float a2 = q < 2 ? (q == 0 ? p[2] : p[6])  : (q == 2 ? p[10] : p[14]);
        float a3 = q < 2 ? (q == 0 ? p[3] : p[7])  : (q == 2 ? p[11] : p[15]);
        #pragma unroll
        for (int off = 8; off >= 1; off >>= 1) {
            a0 += __shfl_xor(a0, off);
            a1 += __shfl_xor(a1, off);
            a2 += __shfl_xor(a2, off);
            a3 += __shfl_xor(a3, off);
        }
        float4 asv = reinterpret_cast<const float4*>(as2)[q];
        float4 adv = reinterpret_cast<const float4*>(ad2)[q];
        float es  = a0 * asv.x + a1 * asv.y + a2 * asv.z + a3 * asv.w;
        float edv = a0 * adv.x + a1 * adv.y + a2 * adv.z + a3 * adv.w;
        es  += __shfl_xor(es, 16);  es  += __shfl_xor(es, 32);
        edv += __shfl_xor(edv, 16); edv += __shfl_xor(edv, 32);
        if ((lane & 15) == 0) {
            float4 hv = make_float4(a0, a1, a2, a3);
            *reinterpret_cast<float4*>(&H2p[(size_t)n * 32 + q * 4]) = hv;
        }
        if (lane == 0) {
            H2p[(size_t)n * 32 + 16] = es;
            ED2[n] = edv;
        }
    }
}

// ---------------- Layer-2 aggregation + bias (fused H2p rows, 2x unroll) ----------------

__global__ __launch_bounds__(256) void agg2_kernel(const float* __restrict__ H2p,
                                                   const float* __restrict__ ED2,
                                                   const int* __restrict__ row_start,
                                                   const int* __restrict__ colB,
                                                   const float* __restrict__ b2,
                                                   float* __restrict__ out, int N) {
    int g = blockIdx.x * 4 + (threadIdx.x >> 6);
    if (g >= N) return;
    int lane = threadIdx.x & 63;
    int ep = lane >> 4;
    unsigned int c4 = (lane & 15) << 2;
    int s0 = row_start[g], s1 = row_start[g + 1];
    float ed = ED2[g];
    const char* H2b = (const char*)H2p;
    float s = 0.f, acc = 0.f, sB = 0.f, accB = 0.f;
    int i = s0 + ep;
    for (; i + 4 < s1; i += 8) {
        unsigned int r0 = ((unsigned int)colB[i]) >> 2;       // src*128 bytes
        unsigned int r1 = ((unsigned int)colB[i + 4]) >> 2;
        float e0 = *(const float*)(H2b + (r0 | 64));          // es slot
        float e1 = *(const float*)(H2b + (r1 | 64));
        float hv0 = *(const float*)(H2b + (r0 | c4));
        float hv1 = *(const float*)(H2b + (r1 | c4));
        e0 += ed; e1 += ed;
        e0 = fmaxf(e0, NEG_SLOPE * e0);
        e1 = fmaxf(e1, NEG_SLOPE * e1);
        float p0 = __expf(e0), p1 = __expf(e1);
        s += p0; sB += p1;
        acc = fmaf(p0, hv0, acc);
        accB = fmaf(p1, hv1, accB);
    }
    if (i < s1) {
        unsigned int r = ((unsigned int)colB[i]) >> 2;
        float e = *(const float*)(H2b + (r | 64));
        float hv = *(const float*)(H2b + (r | c4));
        e += ed;
        e = fmaxf(e, NEG_SLOPE * e);
        float p = __expf(e);
        s += p;
        acc = fmaf(p, hv, acc);
    }
    s += sB; acc += accB;
    s += __shfl_xor(s, 16);
    s += __shfl_xor(s, 32);
    acc += __shfl_xor(acc, 16);
    acc += __shfl_xor(acc, 32);
    if ((lane & 48) == 0) out[(size_t)g * NCLS + (lane & 15)] = acc / s + b2[lane & 15];
}

// ---------------- launch ----------------

extern "C" void kernel_launch(void* const* d_in, const int* in_sizes, int n_in,
                              void* d_out, int out_size, void* d_ws, size_t ws_size,
                              hipStream_t stream) {
    const float* x   = (const float*)d_in[0];
    const int*   ei  = (const int*)d_in[1];
    const float* W1  = (const float*)d_in[2];
    const float* as1 = (const float*)d_in[3];
    const float* ad1 = (const float*)d_in[4];
    const float* b1  = (const float*)d_in[5];
    const float* W2  = (const float*)d_in[6];
    const float* as2 = (const float*)d_in[7];
    const float* ad2 = (const float*)d_in[8];
    const float* b2  = (const float*)d_in[9];
    float* out = (float*)d_out;

    int N = in_sizes[0] / IN_CH;
    int E = in_sizes[1] / 2;
    int Etot = E + N;
    int fill_n = E + 4 * N;
    int nb = (N + 255) / 256;

    char* ws = (char*)d_ws;
    size_t off = 0;
    auto alloc = [&](size_t bytes) -> void* {
        void* p = ws + off;
        off += (bytes + 255) & ~(size_t)255;
        return p;
    };
    unsigned short* Hb    = (unsigned short*)alloc((size_t)(N + 1) * HIDC * 2);
    unsigned short* W1t   = (unsigned short*)alloc((size_t)HIDC * IN_CH * 2);
    float*          W2t32 = (float*)alloc((size_t)HIDC * NCLS * 4);
    float* H2p = (float*)alloc((size_t)(N + 1) * 32 * 4);
    float* ES1 = (float*)alloc((size_t)(N + 1) * 8 * 4);
    float* ED1 = (float*)alloc((size_t)N * 8 * 4);
    float* ED2 = (float*)alloc((size_t)N * 4);
    int* counts = (int*)alloc((size_t)N * 4);
    int* erank  = (int*)alloc((size_t)Etot * 4);
    int* row_start = (int*)alloc((size_t)(N + 1) * 4);
    int* colB = (int*)alloc((size_t)fill_n * 4);
    int* bsums = (int*)alloc((size_t)256 * 4);
    int* bofs  = (int*)alloc((size_t)256 * 4);

    hipMemsetAsync(counts, 0, (size_t)N * 4, stream);

    int eb = (Etot + 255) / 256;
    count_fill_kernel<<<(fill_n + 255) / 256, 256, 0, stream>>>(
        ei, counts, erank, E, Etot, colB, fill_n, N * HIDC * 2,
        Hb, ES1, H2p, W1, W1t, W2, W2t32, N);
    scanA_kernel<<<nb, 256, 0, stream>>>(counts, row_start, bsums, N);
    scanB_kernel<<<1, 256, 0, stream>>>(bsums, bofs, row_start, nb, N);
    scanC_kernel<<<nb, 256, 0, stream>>>(row_start, bofs, N);
    scatter_kernel<<<eb, 256, 0, stream>>>(ei, row_start, erank, colB, E, Etot);

    dim3 g1((N + 127) / 128, 2);
    gemm1_mfma<<<g1, 256, 0, stream>>>(x, W1t, as1, ad1, Hb, ES1, ED1, N);
    agg1_kernel<<<(N + 3) / 4, 256, 0, stream>>>(Hb, ES1, ED1, row_start, colB, b1,
                                                 W2t32, as2, ad2, H2p, ED2, N);
    agg2_kernel<<<(N + 3) / 4, 256, 0, stream>>>(H2p, ED2, row_start, colB, b2, out, N);
}